// Round 9
// baseline (3738.018 us; speedup 1.0000x reference)
//
#include <hip/hip_runtime.h>

#define S_LEN 2048
#define B_SZ  64
#define D_IN  128
#define H_SZ  128
#define G4    512   // 4*H

typedef __attribute__((ext_vector_type(4))) float     floatx4;
typedef __attribute__((ext_vector_type(8))) _Float16  half8;
typedef __attribute__((ext_vector_type(4))) _Float16  half4;

// Barrier draining ONLY lgkmcnt (LDS); global loads/stores stay in flight.
__device__ __forceinline__ void lds_barrier() {
  asm volatile("s_waitcnt lgkmcnt(0)\n\ts_barrier" ::: "memory");
}

// f32x8 -> scaled f16x8
__device__ __forceinline__ half8 wcvt(const float* __restrict__ p, float sc) {
  floatx4 v0 = *(const floatx4*)p;
  floatx4 v1 = *(const floatx4*)(p + 4);
  half8 h;
  h[0] = (_Float16)(v0.x * sc); h[1] = (_Float16)(v0.y * sc);
  h[2] = (_Float16)(v0.z * sc); h[3] = (_Float16)(v0.w * sc);
  h[4] = (_Float16)(v1.x * sc); h[5] = (_Float16)(v1.y * sc);
  h[6] = (_Float16)(v1.z * sc); h[7] = (_Float16)(v1.w * sc);
  return h;
}

// ---------------------------------------------------------------------------
// Kernel 1 (UNCHANGED, harness-verified): gx[b][n][t] = (X·Wih^T + b)·sc(ty),
// f16, transposed to [B][512][S].  sc = -log2e (i,f,o), -2log2e (g).
// ---------------------------------------------------------------------------
__global__ __launch_bounds__(256) void gx_gemm(
    const float* __restrict__ X,       // [S*B][128] (row = t*64+b)
    const float* __restrict__ Wih,     // [512][128]
    const float* __restrict__ bias,    // [512]
    _Float16* __restrict__ gx)         // [64][512][2048] f16, pre-scaled
{
  __shared__ _Float16 Wl[128][136];
  const int tid  = threadIdx.x;
  const int lane = tid & 63;
  const int wv   = tid >> 6;
  const int b    = blockIdx.y;
  const int T0   = blockIdx.x * 256;
  const int m    = lane & 15;
  const int q    = lane >> 4;

  const float LOG2E = 1.4426950408889634f;

  half8 afrag[4][4];
  #pragma unroll
  for (int rg = 0; rg < 4; ++rg) {
    const int t = T0 + rg * 64 + wv * 16 + m;
    const float* xrow = X + ((size_t)t * B_SZ + b) * D_IN;
    #pragma unroll
    for (int kf = 0; kf < 4; ++kf) {
      const int k0 = kf * 32 + q * 8;
      floatx4 v0 = *(const floatx4*)(xrow + k0);
      floatx4 v1 = *(const floatx4*)(xrow + k0 + 4);
      half8 a;
      a[0] = (_Float16)v0.x; a[1] = (_Float16)v0.y;
      a[2] = (_Float16)v0.z; a[3] = (_Float16)v0.w;
      a[4] = (_Float16)v1.x; a[5] = (_Float16)v1.y;
      a[6] = (_Float16)v1.z; a[7] = (_Float16)v1.w;
      afrag[rg][kf] = a;
    }
  }

  for (int nc = 0; nc < 4; ++nc) {
    const float sc = (nc == 2) ? (-2.0f * LOG2E) : (-LOG2E);
    __syncthreads();
    for (int i = tid; i < 128 * 32; i += 256) {
      const int row = i >> 5;
      const int c4  = (i & 31) * 4;
      floatx4 v = *(const floatx4*)(Wih + ((size_t)nc * 128 + row) * D_IN + c4);
      Wl[row][c4 + 0] = (_Float16)v.x;
      Wl[row][c4 + 1] = (_Float16)v.y;
      Wl[row][c4 + 2] = (_Float16)v.z;
      Wl[row][c4 + 3] = (_Float16)v.w;
    }
    __syncthreads();

    #pragma unroll
    for (int nt = 0; nt < 8; ++nt) {
      const int n0  = nc * 128 + nt * 16;
      const int nlo = nt * 16 + m;
      const float bv = bias[n0 + m];
      half8 bfrag[4];
      #pragma unroll
      for (int kf = 0; kf < 4; ++kf)
        bfrag[kf] = *(const half8*)(&Wl[nlo][kf * 32 + q * 8]);
      #pragma unroll
      for (int rg = 0; rg < 4; ++rg) {
        floatx4 acc = {bv, bv, bv, bv};
        #pragma unroll
        for (int kf = 0; kf < 4; ++kf)
          acc = __builtin_amdgcn_mfma_f32_16x16x32_f16(afrag[rg][kf],
                                                       bfrag[kf], acc, 0, 0, 0);
        const int tbase = T0 + rg * 64 + wv * 16 + q * 4;
        half4 hv;
        hv[0] = (_Float16)(acc[0] * sc);
        hv[1] = (_Float16)(acc[1] * sc);
        hv[2] = (_Float16)(acc[2] * sc);
        hv[3] = (_Float16)(acc[3] * sc);
        *(half4*)(gx + ((size_t)b * G4 + n0 + m) * S_LEN + tbase) = hv;
      }
    }
  }
}

// ---------------------------------------------------------------------------
// Kernel 2: ROUND 9 — MFMA recurrence. 16 batches per WG (4 WGs x 512 thr,
// 8 waves).  gates[512x16] = Whh[512x128] x H[128x16] per substep via 128
// mfma_f32_16x16x32_f16 (16/wave) instead of 512 wave-serialized fdot2s.
// Wave w owns hidden col-tile w AND all 4 gate types for it, so i,f,g,o of
// a (col,batch) land in the SAME lane: no DPP butterfly, plain scalar act.
// Fragment layouts mirrored from the verified gx_gemm (A row=lane&15,
// k=(lane>>4)*8; B col=lane&15(=batch); C col=batch,row=(lane>>4)*4+reg).
// C initialized from pre-scaled gx (prefetched 1 quad = 4 substeps ahead).
// h exchange: LDS [16][136] ping-pong + 1 barrier/substep.
// ---------------------------------------------------------------------------

#define PIN_W()                                                               \
  asm volatile(""                                                             \
               : "+v"(wA00), "+v"(wA01), "+v"(wA02), "+v"(wA03),              \
                 "+v"(wA10), "+v"(wA11), "+v"(wA12), "+v"(wA13),              \
                 "+v"(wA20), "+v"(wA21), "+v"(wA22), "+v"(wA23),              \
                 "+v"(wA30), "+v"(wA31), "+v"(wA32), "+v"(wA33))

// load one quad (4 timesteps) of gx for all 16 (ty,r) rows into P##tyr
#define GLOADQ(P, TQ)                                                         \
  P##00 = *(const half4*)(gxb + (size_t)(0 * 128 + 0) * S_LEN + (TQ));        \
  P##01 = *(const half4*)(gxb + (size_t)(0 * 128 + 1) * S_LEN + (TQ));        \
  P##02 = *(const half4*)(gxb + (size_t)(0 * 128 + 2) * S_LEN + (TQ));        \
  P##03 = *(const half4*)(gxb + (size_t)(0 * 128 + 3) * S_LEN + (TQ));        \
  P##10 = *(const half4*)(gxb + (size_t)(1 * 128 + 0) * S_LEN + (TQ));        \
  P##11 = *(const half4*)(gxb + (size_t)(1 * 128 + 1) * S_LEN + (TQ));        \
  P##12 = *(const half4*)(gxb + (size_t)(1 * 128 + 2) * S_LEN + (TQ));        \
  P##13 = *(const half4*)(gxb + (size_t)(1 * 128 + 3) * S_LEN + (TQ));        \
  P##20 = *(const half4*)(gxb + (size_t)(2 * 128 + 0) * S_LEN + (TQ));        \
  P##21 = *(const half4*)(gxb + (size_t)(2 * 128 + 1) * S_LEN + (TQ));        \
  P##22 = *(const half4*)(gxb + (size_t)(2 * 128 + 2) * S_LEN + (TQ));        \
  P##23 = *(const half4*)(gxb + (size_t)(2 * 128 + 3) * S_LEN + (TQ));        \
  P##30 = *(const half4*)(gxb + (size_t)(3 * 128 + 0) * S_LEN + (TQ));        \
  P##31 = *(const half4*)(gxb + (size_t)(3 * 128 + 1) * S_LEN + (TQ));        \
  P##32 = *(const half4*)(gxb + (size_t)(3 * 128 + 2) * S_LEN + (TQ));        \
  P##33 = *(const half4*)(gxb + (size_t)(3 * 128 + 3) * S_LEN + (TQ));

#define GROT()                                                                \
  gc00 = gn00; gc01 = gn01; gc02 = gn02; gc03 = gn03;                         \
  gc10 = gn10; gc11 = gn11; gc12 = gn12; gc13 = gn13;                         \
  gc20 = gn20; gc21 = gn21; gc22 = gn22; gc23 = gn23;                         \
  gc30 = gn30; gc31 = gn31; gc32 = gn32; gc33 = gn33;                         \
  tc0 = tn0; tc1 = tn1; tc2 = tn2; tc3 = tn3;

#define TLOADQ(P, TQ)                                                         \
  P##0 = tmb[(size_t)((TQ) + 0) * B_SZ];                                      \
  P##1 = tmb[(size_t)((TQ) + 1) * B_SZ];                                      \
  P##2 = tmb[(size_t)((TQ) + 2) * B_SZ];                                      \
  P##3 = tmb[(size_t)((TQ) + 3) * B_SZ];

// activation for one hidden col: PI..PO pre-acts (pre-scaled incl gx),
// TMV time, WTR/BTR decay consts, CR running c, HR result h
#define ACT1(PI, PF, PG, PO, TMV, WTR, BTR, CR, HR)                           \
  {                                                                           \
    const float is = __builtin_amdgcn_rcpf(1.0f + __builtin_amdgcn_exp2f(PI));\
    const float fs = __builtin_amdgcn_rcpf(1.0f + __builtin_amdgcn_exp2f(PF));\
    const float gt = fmaf(2.0f,                                               \
        __builtin_amdgcn_rcpf(1.0f + __builtin_amdgcn_exp2f(PG)), -1.0f);     \
    const float os = __builtin_amdgcn_rcpf(1.0f + __builtin_amdgcn_exp2f(PO));\
    const float z  = fminf(fmaf((TMV), (WTR), (BTR)), 0.0f);                  \
    const float d  = __builtin_amdgcn_exp2f(z);                               \
    (CR) = fmaf(fs * d, (CR), is * gt);                                       \
    const float et = __builtin_amdgcn_exp2f(-2.0f * LOG2E * (CR));            \
    const float th = fmaf(2.0f, __builtin_amdgcn_rcpf(1.0f + et), -1.0f);     \
    (HR) = os * th;                                                           \
  }

// one substep: t = tq + K
#define SUBK(K, RP, WP, TMV)                                                  \
  {                                                                           \
    half8 hb0 = *(const half8*)&hl[RP][bq][0 * 32 + q * 8];                   \
    half8 hb1 = *(const half8*)&hl[RP][bq][1 * 32 + q * 8];                   \
    half8 hb2 = *(const half8*)&hl[RP][bq][2 * 32 + q * 8];                   \
    half8 hb3 = *(const half8*)&hl[RP][bq][3 * 32 + q * 8];                   \
    floatx4 aI = {(float)gc00[K], (float)gc01[K], (float)gc02[K], (float)gc03[K]}; \
    floatx4 aF = {(float)gc10[K], (float)gc11[K], (float)gc12[K], (float)gc13[K]}; \
    floatx4 aG = {(float)gc20[K], (float)gc21[K], (float)gc22[K], (float)gc23[K]}; \
    floatx4 aO = {(float)gc30[K], (float)gc31[K], (float)gc32[K], (float)gc33[K]}; \
    aI = __builtin_amdgcn_mfma_f32_16x16x32_f16(wA00, hb0, aI, 0, 0, 0);      \
    aI = __builtin_amdgcn_mfma_f32_16x16x32_f16(wA01, hb1, aI, 0, 0, 0);      \
    aI = __builtin_amdgcn_mfma_f32_16x16x32_f16(wA02, hb2, aI, 0, 0, 0);      \
    aI = __builtin_amdgcn_mfma_f32_16x16x32_f16(wA03, hb3, aI, 0, 0, 0);      \
    aF = __builtin_amdgcn_mfma_f32_16x16x32_f16(wA10, hb0, aF, 0, 0, 0);      \
    aF = __builtin_amdgcn_mfma_f32_16x16x32_f16(wA11, hb1, aF, 0, 0, 0);      \
    aF = __builtin_amdgcn_mfma_f32_16x16x32_f16(wA12, hb2, aF, 0, 0, 0);      \
    aF = __builtin_amdgcn_mfma_f32_16x16x32_f16(wA13, hb3, aF, 0, 0, 0);      \
    aG = __builtin_amdgcn_mfma_f32_16x16x32_f16(wA20, hb0, aG, 0, 0, 0);      \
    aG = __builtin_amdgcn_mfma_f32_16x16x32_f16(wA21, hb1, aG, 0, 0, 0);      \
    aG = __builtin_amdgcn_mfma_f32_16x16x32_f16(wA22, hb2, aG, 0, 0, 0);      \
    aG = __builtin_amdgcn_mfma_f32_16x16x32_f16(wA23, hb3, aG, 0, 0, 0);      \
    aO = __builtin_amdgcn_mfma_f32_16x16x32_f16(wA30, hb0, aO, 0, 0, 0);      \
    aO = __builtin_amdgcn_mfma_f32_16x16x32_f16(wA31, hb1, aO, 0, 0, 0);      \
    aO = __builtin_amdgcn_mfma_f32_16x16x32_f16(wA32, hb2, aO, 0, 0, 0);      \
    aO = __builtin_amdgcn_mfma_f32_16x16x32_f16(wA33, hb3, aO, 0, 0, 0);      \
    float h0, h1, h2, h3;                                                     \
    ACT1(aI[0], aF[0], aG[0], aO[0], (TMV), wt0, bt0, c0, h0);                \
    ACT1(aI[1], aF[1], aG[1], aO[1], (TMV), wt1, bt1, c1, h1);                \
    ACT1(aI[2], aF[2], aG[2], aO[2], (TMV), wt2, bt2, c2, h2);                \
    ACT1(aI[3], aF[3], aG[3], aO[3], (TMV), wt3, bt3, c3, h3);                \
    half4 hv;                                                                 \
    hv[0] = (_Float16)h0; hv[1] = (_Float16)h1;                               \
    hv[2] = (_Float16)h2; hv[3] = (_Float16)h3;                               \
    *(half4*)&hl[WP][bq][hc0] = hv;                                           \
    const int tcur = tq + (K);                                                \
    floatx4 ov = {h0, h1, h2, h3};                                            \
    *(floatx4*)(out + ((size_t)tcur << 13) + ((size_t)b << 7) + hc0) = ov;    \
    if (tcur == 0) {                                                          \
      float* hf = out + (size_t)S_LEN * B_SZ * H_SZ;                          \
      *(floatx4*)(hf + ((size_t)b << 7) + hc0) = ov;                          \
      floatx4 cv = {c0, c1, c2, c3};                                          \
      *(floatx4*)(hf + (size_t)B_SZ * H_SZ + ((size_t)b << 7) + hc0) = cv;    \
    }                                                                         \
    lds_barrier();                                                            \
  }

__global__ __launch_bounds__(512)
__attribute__((amdgpu_waves_per_eu(2, 2)))
void lstm_rev(
    const _Float16* __restrict__ gx,        // [64][512][2048] f16, pre-scaled
    const float* __restrict__ timep,        // [S*B]
    const float* __restrict__ Whh,          // [512][128]
    const float* __restrict__ w_tp,         // [128]
    const float* __restrict__ b_tp,         // [128]
    float* __restrict__ out)                // S*B*H outputs, then h, then c
{
  __shared__ __align__(16) _Float16 hl[2][16][136];   // ping-pong h, padded
  const int tid = threadIdx.x;               // 0..511
  const int w   = tid >> 6;                  // wave = hidden col-tile (0..7)
  const int l   = tid & 63;
  const int bq  = l & 15;                    // batch within WG (B/C col)
  const int q   = l >> 4;                    // 0..3
  const int B0  = blockIdx.x * 16;
  const int b   = B0 + bq;
  const int hc0 = w * 16 + q * 4;            // this lane's 4 hidden cols

  const float LOG2E = 1.4426950408889634f;

  // A-frags: wA[ty][ks] = sc(ty) * Whh[ty*128 + w*16 + (l&15)][ks*32+q*8..+7]
  half8 wA00, wA01, wA02, wA03, wA10, wA11, wA12, wA13;
  half8 wA20, wA21, wA22, wA23, wA30, wA31, wA32, wA33;
  {
    const float s1 = -LOG2E, s2 = -2.0f * LOG2E;
    const float* r0 = Whh + (size_t)(0 * 128 + w * 16 + bq) * H_SZ + q * 8;
    const float* r1 = Whh + (size_t)(1 * 128 + w * 16 + bq) * H_SZ + q * 8;
    const float* r2 = Whh + (size_t)(2 * 128 + w * 16 + bq) * H_SZ + q * 8;
    const float* r3 = Whh + (size_t)(3 * 128 + w * 16 + bq) * H_SZ + q * 8;
    wA00 = wcvt(r0 +  0, s1); wA01 = wcvt(r0 + 32, s1);
    wA02 = wcvt(r0 + 64, s1); wA03 = wcvt(r0 + 96, s1);
    wA10 = wcvt(r1 +  0, s1); wA11 = wcvt(r1 + 32, s1);
    wA12 = wcvt(r1 + 64, s1); wA13 = wcvt(r1 + 96, s1);
    wA20 = wcvt(r2 +  0, s2); wA21 = wcvt(r2 + 32, s2);
    wA22 = wcvt(r2 + 64, s2); wA23 = wcvt(r2 + 96, s2);
    wA30 = wcvt(r3 +  0, s1); wA31 = wcvt(r3 + 32, s1);
    wA32 = wcvt(r3 + 64, s1); wA33 = wcvt(r3 + 96, s1);
  }

  // per-col decay constants
  const floatx4 wtv = *(const floatx4*)(w_tp + hc0);
  const floatx4 btv = *(const floatx4*)(b_tp + hc0);
  const float wt0 = -LOG2E * wtv[0], wt1 = -LOG2E * wtv[1];
  const float wt2 = -LOG2E * wtv[2], wt3 = -LOG2E * wtv[3];
  const float bt0 = -LOG2E * btv[0], bt1 = -LOG2E * btv[1];
  const float bt2 = -LOG2E * btv[2], bt3 = -LOG2E * btv[3];

  // zero both h buffers
  for (int i = tid; i < 2 * 16 * 136; i += 512)
    ((_Float16*)hl)[i] = (_Float16)0.0f;
  __syncthreads();

  // gx base for this lane: gx[b][w*16 + q*4 + ...][t]
  const _Float16* gxb = gx + ((size_t)b * G4 + w * 16 + q * 4) * S_LEN;
  const float*    tmb = timep + b;

  float c0 = 0.0f, c1 = 0.0f, c2 = 0.0f, c3 = 0.0f;

  // quad prefetch: gc = quad blk (ready), gn = quad blk-1 (in flight)
  half4 gc00, gc01, gc02, gc03, gc10, gc11, gc12, gc13;
  half4 gc20, gc21, gc22, gc23, gc30, gc31, gc32, gc33;
  half4 gn00, gn01, gn02, gn03, gn10, gn11, gn12, gn13;
  half4 gn20, gn21, gn22, gn23, gn30, gn31, gn32, gn33;
  float tc0, tc1, tc2, tc3, tn0, tn1, tn2, tn3;
  GLOADQ(gc, 511 * 4)
  TLOADQ(tc, 511 * 4)
  GLOADQ(gn, 510 * 4)
  TLOADQ(tn, 510 * 4)

  for (int blk = 511; blk >= 0; --blk) {
    const int tq = blk * 4;
    PIN_W();
    // substeps t = tq+3 .. tq (ping-pong parity returns to 0 each quad)
    SUBK(3, 0, 1, tc3)
    SUBK(2, 1, 0, tc2)
    SUBK(1, 0, 1, tc1)
    SUBK(0, 1, 0, tc0)
    // rotate prefetch: gc <- blk-1, issue gn <- blk-2
    GROT()
    const int pfb = (blk >= 2) ? (blk - 2) * 4 : 0;
    GLOADQ(gn, pfb)
    TLOADQ(tn, pfb)
  }
}

// ---------------------------------------------------------------------------
extern "C" void kernel_launch(void* const* d_in, const int* in_sizes, int n_in,
                              void* d_out, int out_size, void* d_ws, size_t ws_size,
                              hipStream_t stream) {
  const float* input = (const float*)d_in[0];   // (S,B,D)
  const float* timep = (const float*)d_in[1];   // (S,B,1)
  const float* W_ih  = (const float*)d_in[2];   // (4H,D)
  const float* W_hh  = (const float*)d_in[3];   // (4H,H)
  const float* bias  = (const float*)d_in[4];   // (4H,)
  const float* w_t   = (const float*)d_in[5];   // (H,)
  const float* b_t   = (const float*)d_in[6];   // (H,)
  float* out = (float*)d_out;

  _Float16* gx = (_Float16*)d_ws;   // 64*512*2048*2 = 128 MiB, [b][n][t]

  gx_gemm<<<dim3(S_LEN / 256, B_SZ), dim3(256), 0, stream>>>(
      input, W_ih, bias, gx);

  lstm_rev<<<dim3(B_SZ / 16), dim3(512), 0, stream>>>(
      gx, timep, W_hh, w_t, b_t, out);
}

// Round 10
// 2104.366 us; speedup vs baseline: 1.7763x; 1.7763x over previous
//
#include <hip/hip_runtime.h>

#define S_LEN 2048
#define B_SZ  64
#define D_IN  128
#define H_SZ  128
#define G4    512   // 4*H

typedef __attribute__((ext_vector_type(4))) float     floatx4;
typedef __attribute__((ext_vector_type(8))) _Float16  half8;
typedef __attribute__((ext_vector_type(4))) _Float16  half4;
typedef __attribute__((ext_vector_type(2))) _Float16  half2_t;

// DPP quad_perm helper (VALU pipe). CTRL: xor1=0xB1, xor2=0x4E.
template<int CTRL>
__device__ __forceinline__ float qperm(float v) {
  return __int_as_float(
      __builtin_amdgcn_mov_dpp(__float_as_int(v), CTRL, 0xF, 0xF, true));
}

template<int P>
__device__ __forceinline__ half2_t h2ext(half8 v) {
  return __builtin_shufflevector(v, v, 2 * P, 2 * P + 1);
}

// Barrier draining ONLY lgkmcnt (LDS); global loads/stores stay in flight.
__device__ __forceinline__ void lds_barrier() {
  asm volatile("s_waitcnt lgkmcnt(0)\n\ts_barrier" ::: "memory");
}

// ---------------------------------------------------------------------------
// Kernel 1 (unchanged, harness-verified): gx[b][n][t] = (X·Wih^T + b)·sc(ty),
// f16, transposed to [B][512][S].  sc = -log2e (i,f,o), -2log2e (g).
// ---------------------------------------------------------------------------
__global__ __launch_bounds__(256) void gx_gemm(
    const float* __restrict__ X,       // [S*B][128] (row = t*64+b)
    const float* __restrict__ Wih,     // [512][128]
    const float* __restrict__ bias,    // [512]
    _Float16* __restrict__ gx)         // [64][512][2048] f16, pre-scaled
{
  __shared__ _Float16 Wl[128][136];
  const int tid  = threadIdx.x;
  const int lane = tid & 63;
  const int wv   = tid >> 6;
  const int b    = blockIdx.y;
  const int T0   = blockIdx.x * 256;
  const int m    = lane & 15;
  const int q    = lane >> 4;

  const float LOG2E = 1.4426950408889634f;

  half8 afrag[4][4];
  #pragma unroll
  for (int rg = 0; rg < 4; ++rg) {
    const int t = T0 + rg * 64 + wv * 16 + m;
    const float* xrow = X + ((size_t)t * B_SZ + b) * D_IN;
    #pragma unroll
    for (int kf = 0; kf < 4; ++kf) {
      const int k0 = kf * 32 + q * 8;
      floatx4 v0 = *(const floatx4*)(xrow + k0);
      floatx4 v1 = *(const floatx4*)(xrow + k0 + 4);
      half8 a;
      a[0] = (_Float16)v0.x; a[1] = (_Float16)v0.y;
      a[2] = (_Float16)v0.z; a[3] = (_Float16)v0.w;
      a[4] = (_Float16)v1.x; a[5] = (_Float16)v1.y;
      a[6] = (_Float16)v1.z; a[7] = (_Float16)v1.w;
      afrag[rg][kf] = a;
    }
  }

  for (int nc = 0; nc < 4; ++nc) {
    const float sc = (nc == 2) ? (-2.0f * LOG2E) : (-LOG2E);
    __syncthreads();
    for (int i = tid; i < 128 * 32; i += 256) {
      const int row = i >> 5;
      const int c4  = (i & 31) * 4;
      floatx4 v = *(const floatx4*)(Wih + ((size_t)nc * 128 + row) * D_IN + c4);
      Wl[row][c4 + 0] = (_Float16)v.x;
      Wl[row][c4 + 1] = (_Float16)v.y;
      Wl[row][c4 + 2] = (_Float16)v.z;
      Wl[row][c4 + 3] = (_Float16)v.w;
    }
    __syncthreads();

    #pragma unroll
    for (int nt = 0; nt < 8; ++nt) {
      const int n0  = nc * 128 + nt * 16;
      const int nlo = nt * 16 + m;
      const float bv = bias[n0 + m];
      half8 bfrag[4];
      #pragma unroll
      for (int kf = 0; kf < 4; ++kf)
        bfrag[kf] = *(const half8*)(&Wl[nlo][kf * 32 + q * 8]);
      #pragma unroll
      for (int rg = 0; rg < 4; ++rg) {
        floatx4 acc = {bv, bv, bv, bv};
        #pragma unroll
        for (int kf = 0; kf < 4; ++kf)
          acc = __builtin_amdgcn_mfma_f32_16x16x32_f16(afrag[rg][kf],
                                                       bfrag[kf], acc, 0, 0, 0);
        const int tbase = T0 + rg * 64 + wv * 16 + q * 4;
        half4 hv;
        hv[0] = (_Float16)(acc[0] * sc);
        hv[1] = (_Float16)(acc[1] * sc);
        hv[2] = (_Float16)(acc[2] * sc);
        hv[3] = (_Float16)(acc[3] * sc);
        *(half4*)(gx + ((size_t)b * G4 + n0 + m) * S_LEN + tbase) = hv;
      }
    }
  }
}

// ---------------------------------------------------------------------------
// Kernel 2: ROUND 10 — R6 structure (best, 1121us) with TWO batches per WG
// in DIFFERENT WAVES: 1024 threads, threads 0-511 = batch A (code identical
// to R6), 512-1023 = batch B. Each SIMD hosts 4 waves (2 per batch) whose
// serial chains are independent -> batch B's waves issue while batch A's
// stall on ds_read/act latency (the ~65% stall R4-R8 could never remove,
// because same-batch waves are barrier-locked to the same chain). One
// barrier covers both batches. Weights are batch-independent: no VGPR
// duplication (~88-100 regs, under the 128/wave budget of waves_per_eu(4)).
// Disambiguation: big drop => stall-fill confirmed; flat => issue-bound.
// types: 0=i 1=f 2=g 3=o
// ---------------------------------------------------------------------------
__device__ __forceinline__ float fd(half2_t a, half2_t b, float c) {
  return __builtin_amdgcn_fdot2(a, b, c, false);
}

__device__ __forceinline__ half8 wcvt(const float* __restrict__ p, float sc) {
  floatx4 v0 = *(const floatx4*)p;
  floatx4 v1 = *(const floatx4*)(p + 4);
  half8 h;
  h[0] = (_Float16)(v0.x * sc); h[1] = (_Float16)(v0.y * sc);
  h[2] = (_Float16)(v0.z * sc); h[3] = (_Float16)(v0.w * sc);
  h[4] = (_Float16)(v1.x * sc); h[5] = (_Float16)(v1.y * sc);
  h[6] = (_Float16)(v1.z * sc); h[7] = (_Float16)(v1.w * sc);
  return h;
}

#define PIN_WEIGHTS()                                                         \
  asm volatile(""                                                             \
               : "+v"(w00), "+v"(w01), "+v"(w02), "+v"(w03),                  \
                 "+v"(w10), "+v"(w11), "+v"(w12), "+v"(w13),                  \
                 "+v"(w20), "+v"(w21), "+v"(w22), "+v"(w23),                  \
                 "+v"(w30), "+v"(w31), "+v"(w32), "+v"(w33),                  \
                 "+v"(wt), "+v"(bt))

#define DOT8(HV, WA, WB, WC, WD)                                              \
  {                                                                           \
    q0a = fd(h2ext<0>(HV), h2ext<0>(WA), q0a);                                \
    q1a = fd(h2ext<0>(HV), h2ext<0>(WB), q1a);                                \
    q2a = fd(h2ext<0>(HV), h2ext<0>(WC), q2a);                                \
    q3a = fd(h2ext<0>(HV), h2ext<0>(WD), q3a);                                \
    q0a = fd(h2ext<1>(HV), h2ext<1>(WA), q0a);                                \
    q1a = fd(h2ext<1>(HV), h2ext<1>(WB), q1a);                                \
    q2a = fd(h2ext<1>(HV), h2ext<1>(WC), q2a);                                \
    q3a = fd(h2ext<1>(HV), h2ext<1>(WD), q3a);                                \
    q0b = fd(h2ext<2>(HV), h2ext<2>(WA), q0b);                                \
    q1b = fd(h2ext<2>(HV), h2ext<2>(WB), q1b);                                \
    q2b = fd(h2ext<2>(HV), h2ext<2>(WC), q2b);                                \
    q3b = fd(h2ext<2>(HV), h2ext<2>(WD), q3b);                                \
    q0b = fd(h2ext<3>(HV), h2ext<3>(WA), q0b);                                \
    q1b = fd(h2ext<3>(HV), h2ext<3>(WB), q1b);                                \
    q2b = fd(h2ext<3>(HV), h2ext<3>(WC), q2b);                                \
    q3b = fd(h2ext<3>(HV), h2ext<3>(WD), q3b);                                \
  }

// Full gate pipeline for one step (identical to R6's verified GATE).
#define GATE(HR, GXV, TMV, CVAR, HVAR)                                        \
  {                                                                           \
    half8 hv0 = *(const half8*)((HR) + 0 * 32 + tt * 8);                      \
    half8 hv1 = *(const half8*)((HR) + 1 * 32 + tt * 8);                      \
    half8 hv2 = *(const half8*)((HR) + 2 * 32 + tt * 8);                      \
    half8 hv3 = *(const half8*)((HR) + 3 * 32 + tt * 8);                      \
    float q0a = 0.f, q0b = 0.f, q1a = 0.f, q1b = 0.f;                         \
    float q2a = 0.f, q2b = 0.f, q3a = 0.f, q3b = 0.f;                         \
    DOT8(hv0, w00, w10, w20, w30);                                            \
    DOT8(hv1, w01, w11, w21, w31);                                            \
    DOT8(hv2, w02, w12, w22, w32);                                            \
    DOT8(hv3, w03, w13, w23, w33);                                            \
    float a0 = q0a + q0b, a1 = q1a + q1b, a2 = q2a + q2b, a3 = q3a + q3b;     \
    a0 += qperm<0xB1>(a0); a1 += qperm<0xB1>(a1);                             \
    a2 += qperm<0xB1>(a2); a3 += qperm<0xB1>(a3);                             \
    a0 += qperm<0x4E>(a0); a1 += qperm<0x4E>(a1);                             \
    a2 += qperm<0x4E>(a2); a3 += qperm<0x4E>(a3);                             \
    float pre = (tt & 1) ? ((tt & 2) ? a3 : a1) : ((tt & 2) ? a2 : a0);       \
    pre += (GXV);  /* already scaled by -log2e (or -2log2e for g) */          \
    const float e  = __builtin_amdgcn_exp2f(pre);                             \
    const float v  = fmaf(am, __builtin_amdgcn_rcpf(1.0f + e), aa);           \
    float z = fmaf((TMV), wt, bt);           /* = -log2e*(t*w_t+b_t) */       \
    z = fminf(z, 0.0f);                      /* -log2e*relu(.) */             \
    const float d  = __builtin_amdgcn_exp2f(z);                               \
    const float p2 = qperm<0x4E>(v);                                          \
    const float fv = (tt == 1) ? v : p2;                                      \
    const float r  = odd ? fv * (d * (CVAR)) : v * p2;                        \
    const float cn = r + qperm<0xB1>(r);                                      \
    (CVAR) = cn;                                                              \
    const float e2 = __builtin_amdgcn_exp2f(-2.0f * LOG2E * cn);              \
    const float th = fmaf(2.0f, __builtin_amdgcn_rcpf(1.0f + e2), -1.0f);     \
    (HVAR) = v * th;                                                          \
  }

// One substep for this thread's batch. K: lane into cur8 (t = blk*8+K).
#define SUB(K, TMV, RP, WP)                                                   \
  {                                                                           \
    const float g0 = (float)cur8[K];                                          \
    float h0;                                                                 \
    GATE(&hbuf[bsel][RP][0], g0, (TMV), c, h0);                               \
    if (tt == 3) {                                                            \
      hbuf[bsel][WP][col] = (_Float16)h0;                                     \
      const int tcur = blk * 8 + K;                                           \
      out[((size_t)tcur << 13) + bH + col] = h0;                              \
      if (tcur == 0) {                                                        \
        float* hf = out + (size_t)S_LEN * B_SZ * H_SZ;                        \
        hf[bH + col] = h0;                                                    \
        hf[(size_t)B_SZ * H_SZ + bH + col] = c;                               \
      }                                                                       \
    }                                                                         \
    lds_barrier();                                                            \
  }

__global__ __launch_bounds__(1024)
__attribute__((amdgpu_waves_per_eu(4, 4)))
void lstm_rev(
    const _Float16* __restrict__ gx,        // [64][512][2048] f16, pre-scaled
    const float* __restrict__ timep,        // [S*B]
    const float* __restrict__ Whh,          // [512][128]
    const float* __restrict__ w_tp,         // [128]
    const float* __restrict__ b_tp,         // [128]
    float* __restrict__ out)                // S*B*H outputs, then h, then c
{
  __shared__ __align__(16) _Float16 hbuf[2][2][H_SZ];  // [batch][pp][col]
  __shared__ __align__(16) float    tml[2][S_LEN];     // staged time, 16KB
  const int tid  = threadIdx.x;              // 0..1023
  const int bsel = tid >> 9;                 // 0 = batch A, 1 = batch B
  const int stid = tid & 511;                // R6-identical sub-thread id
  const int b    = blockIdx.x * 2 + bsel;
  const int tt   = stid & 3;
  const int col  = stid >> 2;
  const int j    = tt * 128 + col;

  const float LOG2E = 1.4426950408889634f;

  // Stage this batch's time column into LDS (4 loads/thread).
  #pragma unroll
  for (int k = 0; k < 4; ++k) {
    const int idx = stid + k * 512;
    tml[bsel][idx] = timep[(idx << 6) + b];
  }

  // Pre-scaled f16 weights in 16 NAMED registers (batch-independent):
  // wTI = sc(T) * W_hh[T*128+col][I*32+tt*8 .. +7].
  half8 w00, w01, w02, w03, w10, w11, w12, w13;
  half8 w20, w21, w22, w23, w30, w31, w32, w33;
  {
    const float s1 = -LOG2E, s2 = -2.0f * LOG2E;
    const float* r0 = Whh + (size_t)(0 * 128 + col) * H_SZ + tt * 8;
    const float* r1 = Whh + (size_t)(1 * 128 + col) * H_SZ + tt * 8;
    const float* r2 = Whh + (size_t)(2 * 128 + col) * H_SZ + tt * 8;
    const float* r3 = Whh + (size_t)(3 * 128 + col) * H_SZ + tt * 8;
    w00 = wcvt(r0 +  0, s1); w01 = wcvt(r0 + 32, s1);
    w02 = wcvt(r0 + 64, s1); w03 = wcvt(r0 + 96, s1);
    w10 = wcvt(r1 +  0, s1); w11 = wcvt(r1 + 32, s1);
    w12 = wcvt(r1 + 64, s1); w13 = wcvt(r1 + 96, s1);
    w20 = wcvt(r2 +  0, s2); w21 = wcvt(r2 + 32, s2);
    w22 = wcvt(r2 + 64, s2); w23 = wcvt(r2 + 96, s2);
    w30 = wcvt(r3 +  0, s1); w31 = wcvt(r3 + 32, s1);
    w32 = wcvt(r3 + 64, s1); w33 = wcvt(r3 + 96, s1);
  }

  float wt = -LOG2E * w_tp[col];
  float bt = -LOG2E * b_tp[col];
  const float am  = (tt == 2) ? 2.0f : 1.0f;
  const float aa  = (tt == 2) ? -1.0f : 0.0f;
  const bool  odd = (tt & 1) != 0;

  if (tid < 2 * 2 * H_SZ) ((_Float16*)hbuf)[tid] = (_Float16)0.0f;
  __syncthreads();

  // This thread's gate-x row (transposed layout): 2048 consecutive f16.
  const _Float16* gxr = gx + ((size_t)b * G4 + j) * S_LEN;
  const size_t bH = (size_t)b * H_SZ;

  // Double-buffered half8 blocks, 2 blocks (~16 substeps) ahead of use.
  half8 cur8 = *(const half8*)(gxr + 255 * 8);
  half8 nxt8 = *(const half8*)(gxr + 254 * 8);

  float c = 0.0f;

  for (int blk = 255; blk >= 0; --blk) {
    PIN_WEIGHTS();
    const int pfb = (blk >= 2) ? blk - 2 : 0;
    half8 fut8 = *(const half8*)(gxr + pfb * 8);
    const floatx4 tmA = *(const floatx4*)(&tml[bsel][blk * 8 + 4]); // +4..+7
    const floatx4 tmB = *(const floatx4*)(&tml[bsel][blk * 8 + 0]); // +0..+3

    // 8 substeps: t = blk*8+7 down to blk*8 (ping-pong parity returns to 0)
    SUB(7, tmA.w, 0, 1)
    SUB(6, tmA.z, 1, 0)
    SUB(5, tmA.y, 0, 1)
    SUB(4, tmA.x, 1, 0)
    SUB(3, tmB.w, 0, 1)
    SUB(2, tmB.z, 1, 0)
    SUB(1, tmB.y, 0, 1)
    SUB(0, tmB.x, 1, 0)

    cur8 = nxt8;
    nxt8 = fut8;
  }
}

// ---------------------------------------------------------------------------
extern "C" void kernel_launch(void* const* d_in, const int* in_sizes, int n_in,
                              void* d_out, int out_size, void* d_ws, size_t ws_size,
                              hipStream_t stream) {
  const float* input = (const float*)d_in[0];   // (S,B,D)
  const float* timep = (const float*)d_in[1];   // (S,B,1)
  const float* W_ih  = (const float*)d_in[2];   // (4H,D)
  const float* W_hh  = (const float*)d_in[3];   // (4H,H)
  const float* bias  = (const float*)d_in[4];   // (4H,)
  const float* w_t   = (const float*)d_in[5];   // (H,)
  const float* b_t   = (const float*)d_in[6];   // (H,)
  float* out = (float*)d_out;

  _Float16* gx = (_Float16*)d_ws;   // 64*512*2048*2 = 128 MiB, [b][n][t]

  gx_gemm<<<dim3(S_LEN / 256, B_SZ), dim3(256), 0, stream>>>(
      input, W_ih, bias, gx);

  lstm_rev<<<dim3(B_SZ / 2), dim3(1024), 0, stream>>>(
      gx, timep, W_hh, w_t, b_t, out);
}

// Round 11
// 1271.129 us; speedup vs baseline: 2.9407x; 1.6555x over previous
//
#include <hip/hip_runtime.h>

#define S_LEN 2048
#define B_SZ  64
#define D_IN  128
#define H_SZ  128
#define G4    512   // 4*H

typedef __attribute__((ext_vector_type(4))) float     floatx4;
typedef __attribute__((ext_vector_type(8))) _Float16  half8;
typedef __attribute__((ext_vector_type(4))) _Float16  half4;
typedef __attribute__((ext_vector_type(2))) _Float16  half2_t;

// DPP quad_perm helper (VALU pipe). CTRL: xor1=0xB1, xor2=0x4E.
template<int CTRL>
__device__ __forceinline__ float qperm(float v) {
  return __int_as_float(
      __builtin_amdgcn_mov_dpp(__float_as_int(v), CTRL, 0xF, 0xF, true));
}

template<int P>
__device__ __forceinline__ half2_t h2ext(half8 v) {
  return __builtin_shufflevector(v, v, 2 * P, 2 * P + 1);
}

// Barrier draining ONLY lgkmcnt (LDS); global loads/stores stay in flight.
__device__ __forceinline__ void lds_barrier() {
  asm volatile("s_waitcnt lgkmcnt(0)\n\ts_barrier" ::: "memory");
}

// ---------------------------------------------------------------------------
// Kernel 1 (unchanged, harness-verified): gx[b][n][t] = (X·Wih^T + b)·sc(ty),
// f16, transposed to [B][512][S].  sc = -log2e (i,f,o), -2log2e (g).
// ---------------------------------------------------------------------------
__global__ __launch_bounds__(256) void gx_gemm(
    const float* __restrict__ X,       // [S*B][128] (row = t*64+b)
    const float* __restrict__ Wih,     // [512][128]
    const float* __restrict__ bias,    // [512]
    _Float16* __restrict__ gx)         // [64][512][2048] f16, pre-scaled
{
  __shared__ _Float16 Wl[128][136];
  const int tid  = threadIdx.x;
  const int lane = tid & 63;
  const int wv   = tid >> 6;
  const int b    = blockIdx.y;
  const int T0   = blockIdx.x * 256;
  const int m    = lane & 15;
  const int q    = lane >> 4;

  const float LOG2E = 1.4426950408889634f;

  half8 afrag[4][4];
  #pragma unroll
  for (int rg = 0; rg < 4; ++rg) {
    const int t = T0 + rg * 64 + wv * 16 + m;
    const float* xrow = X + ((size_t)t * B_SZ + b) * D_IN;
    #pragma unroll
    for (int kf = 0; kf < 4; ++kf) {
      const int k0 = kf * 32 + q * 8;
      floatx4 v0 = *(const floatx4*)(xrow + k0);
      floatx4 v1 = *(const floatx4*)(xrow + k0 + 4);
      half8 a;
      a[0] = (_Float16)v0.x; a[1] = (_Float16)v0.y;
      a[2] = (_Float16)v0.z; a[3] = (_Float16)v0.w;
      a[4] = (_Float16)v1.x; a[5] = (_Float16)v1.y;
      a[6] = (_Float16)v1.z; a[7] = (_Float16)v1.w;
      afrag[rg][kf] = a;
    }
  }

  for (int nc = 0; nc < 4; ++nc) {
    const float sc = (nc == 2) ? (-2.0f * LOG2E) : (-LOG2E);
    __syncthreads();
    for (int i = tid; i < 128 * 32; i += 256) {
      const int row = i >> 5;
      const int c4  = (i & 31) * 4;
      floatx4 v = *(const floatx4*)(Wih + ((size_t)nc * 128 + row) * D_IN + c4);
      Wl[row][c4 + 0] = (_Float16)v.x;
      Wl[row][c4 + 1] = (_Float16)v.y;
      Wl[row][c4 + 2] = (_Float16)v.z;
      Wl[row][c4 + 3] = (_Float16)v.w;
    }
    __syncthreads();

    #pragma unroll
    for (int nt = 0; nt < 8; ++nt) {
      const int n0  = nc * 128 + nt * 16;
      const int nlo = nt * 16 + m;
      const float bv = bias[n0 + m];
      half8 bfrag[4];
      #pragma unroll
      for (int kf = 0; kf < 4; ++kf)
        bfrag[kf] = *(const half8*)(&Wl[nlo][kf * 32 + q * 8]);
      #pragma unroll
      for (int rg = 0; rg < 4; ++rg) {
        floatx4 acc = {bv, bv, bv, bv};
        #pragma unroll
        for (int kf = 0; kf < 4; ++kf)
          acc = __builtin_amdgcn_mfma_f32_16x16x32_f16(afrag[rg][kf],
                                                       bfrag[kf], acc, 0, 0, 0);
        const int tbase = T0 + rg * 64 + wv * 16 + q * 4;
        half4 hv;
        hv[0] = (_Float16)(acc[0] * sc);
        hv[1] = (_Float16)(acc[1] * sc);
        hv[2] = (_Float16)(acc[2] * sc);
        hv[3] = (_Float16)(acc[3] * sc);
        *(half4*)(gx + ((size_t)b * G4 + n0 + m) * S_LEN + tbase) = hv;
      }
    }
  }
}

// ---------------------------------------------------------------------------
// Kernel 2: ROUND 11 — R6 (best, 1121us) + the AGPR-shuffle fix.
// Diagnosis: VGPR_Count=64<66 pinned regs (R10) proves the allocator parks
// the weights in AGPRs (unified file, not in VGPR_Count) and re-reads them
// via v_accvgpr_read every substep (~64 VALU ops on the serial chain) —
// the invariant ~1350cy/substep across R4/5/6/8/10. Fix:
//  (1) PIN_WEIGHTS before EVERY DOT8 group (4x/substep): AGPR round-trips
//      would now cost ~512 moves/substep vs 66 resident arch regs.
//  (2) Pin the 4 hv fragments together after their loads: all 4
//      ds_read_b128 in flight with ONE lgkmcnt wait (~120cy once, was ~4
//      serialized read-use chains), values non-rematerializable.
// Everything else identical to R6. Validity gate: VGPR_Count >= 110.
// types: 0=i 1=f 2=g 3=o
// ---------------------------------------------------------------------------
__device__ __forceinline__ float fd(half2_t a, half2_t b, float c) {
  return __builtin_amdgcn_fdot2(a, b, c, false);
}

__device__ __forceinline__ half8 wcvt(const float* __restrict__ p, float sc) {
  floatx4 v0 = *(const floatx4*)p;
  floatx4 v1 = *(const floatx4*)(p + 4);
  half8 h;
  h[0] = (_Float16)(v0.x * sc); h[1] = (_Float16)(v0.y * sc);
  h[2] = (_Float16)(v0.z * sc); h[3] = (_Float16)(v0.w * sc);
  h[4] = (_Float16)(v1.x * sc); h[5] = (_Float16)(v1.y * sc);
  h[6] = (_Float16)(v1.z * sc); h[7] = (_Float16)(v1.w * sc);
  return h;
}

#define PIN_WEIGHTS()                                                         \
  asm volatile(""                                                             \
               : "+v"(w00), "+v"(w01), "+v"(w02), "+v"(w03),                  \
                 "+v"(w10), "+v"(w11), "+v"(w12), "+v"(w13),                  \
                 "+v"(w20), "+v"(w21), "+v"(w22), "+v"(w23),                  \
                 "+v"(w30), "+v"(w31), "+v"(w32), "+v"(w33),                  \
                 "+v"(wt), "+v"(bt))

#define DOT8(HV, WA, WB, WC, WD)                                              \
  {                                                                           \
    q0a = fd(h2ext<0>(HV), h2ext<0>(WA), q0a);                                \
    q1a = fd(h2ext<0>(HV), h2ext<0>(WB), q1a);                                \
    q2a = fd(h2ext<0>(HV), h2ext<0>(WC), q2a);                                \
    q3a = fd(h2ext<0>(HV), h2ext<0>(WD), q3a);                                \
    q0a = fd(h2ext<1>(HV), h2ext<1>(WA), q0a);                                \
    q1a = fd(h2ext<1>(HV), h2ext<1>(WB), q1a);                                \
    q2a = fd(h2ext<1>(HV), h2ext<1>(WC), q2a);                                \
    q3a = fd(h2ext<1>(HV), h2ext<1>(WD), q3a);                                \
    q0b = fd(h2ext<2>(HV), h2ext<2>(WA), q0b);                                \
    q1b = fd(h2ext<2>(HV), h2ext<2>(WB), q1b);                                \
    q2b = fd(h2ext<2>(HV), h2ext<2>(WC), q2b);                                \
    q3b = fd(h2ext<2>(HV), h2ext<2>(WD), q3b);                                \
    q0b = fd(h2ext<3>(HV), h2ext<3>(WA), q0b);                                \
    q1b = fd(h2ext<3>(HV), h2ext<3>(WB), q1b);                                \
    q2b = fd(h2ext<3>(HV), h2ext<3>(WC), q2b);                                \
    q3b = fd(h2ext<3>(HV), h2ext<3>(WD), q3b);                                \
  }

// Full gate pipeline for one step. hv loads batched (one lgkm wait) and
// pinned; weights pinned before every DOT8 group.
#define GATE(HR, GXV, TMV, CVAR, HVAR)                                        \
  {                                                                           \
    half8 hv0 = *(const half8*)((HR) + 0 * 32 + tt * 8);                      \
    half8 hv1 = *(const half8*)((HR) + 1 * 32 + tt * 8);                      \
    half8 hv2 = *(const half8*)((HR) + 2 * 32 + tt * 8);                      \
    half8 hv3 = *(const half8*)((HR) + 3 * 32 + tt * 8);                      \
    asm volatile("" : "+v"(hv0), "+v"(hv1), "+v"(hv2), "+v"(hv3));            \
    float q0a = 0.f, q0b = 0.f, q1a = 0.f, q1b = 0.f;                         \
    float q2a = 0.f, q2b = 0.f, q3a = 0.f, q3b = 0.f;                         \
    PIN_WEIGHTS();                                                            \
    DOT8(hv0, w00, w10, w20, w30);                                            \
    PIN_WEIGHTS();                                                            \
    DOT8(hv1, w01, w11, w21, w31);                                            \
    PIN_WEIGHTS();                                                            \
    DOT8(hv2, w02, w12, w22, w32);                                            \
    PIN_WEIGHTS();                                                            \
    DOT8(hv3, w03, w13, w23, w33);                                            \
    float a0 = q0a + q0b, a1 = q1a + q1b, a2 = q2a + q2b, a3 = q3a + q3b;     \
    a0 += qperm<0xB1>(a0); a1 += qperm<0xB1>(a1);                             \
    a2 += qperm<0xB1>(a2); a3 += qperm<0xB1>(a3);                             \
    a0 += qperm<0x4E>(a0); a1 += qperm<0x4E>(a1);                             \
    a2 += qperm<0x4E>(a2); a3 += qperm<0x4E>(a3);                             \
    float pre = (tt & 1) ? ((tt & 2) ? a3 : a1) : ((tt & 2) ? a2 : a0);       \
    pre += (GXV);  /* already scaled by -log2e (or -2log2e for g) */          \
    const float e  = __builtin_amdgcn_exp2f(pre);                             \
    const float v  = fmaf(am, __builtin_amdgcn_rcpf(1.0f + e), aa);           \
    float z = fmaf((TMV), wt, bt);           /* = -log2e*(t*w_t+b_t) */       \
    z = fminf(z, 0.0f);                      /* -log2e*relu(.) */             \
    const float d  = __builtin_amdgcn_exp2f(z);                               \
    const float p2 = qperm<0x4E>(v);                                          \
    const float fv = (tt == 1) ? v : p2;                                      \
    const float r  = odd ? fv * (d * (CVAR)) : v * p2;                        \
    const float cn = r + qperm<0xB1>(r);                                      \
    (CVAR) = cn;                                                              \
    const float e2 = __builtin_amdgcn_exp2f(-2.0f * LOG2E * cn);              \
    const float th = fmaf(2.0f, __builtin_amdgcn_rcpf(1.0f + e2), -1.0f);     \
    (HVAR) = v * th;                                                          \
  }

// One substep. K: lane into cur8 (t = blk*8+K).
#define SUB(K, TMV, RP, WP)                                                   \
  {                                                                           \
    const float g0 = (float)cur8[K];                                          \
    float h0;                                                                 \
    GATE(&hbuf[RP][0], g0, (TMV), c, h0);                                     \
    if (tt == 3) {                                                            \
      hbuf[WP][col] = (_Float16)h0;                                           \
      const int tcur = blk * 8 + K;                                           \
      out[((size_t)tcur << 13) + bH + col] = h0;                              \
      if (tcur == 0) {                                                        \
        float* hf = out + (size_t)S_LEN * B_SZ * H_SZ;                        \
        hf[bH + col] = h0;                                                    \
        hf[(size_t)B_SZ * H_SZ + bH + col] = c;                               \
      }                                                                       \
    }                                                                         \
    lds_barrier();                                                            \
  }

__global__ __launch_bounds__(512)
__attribute__((amdgpu_waves_per_eu(2, 2)))
void lstm_rev(
    const _Float16* __restrict__ gx,        // [64][512][2048] f16, pre-scaled
    const float* __restrict__ timep,        // [S*B]
    const float* __restrict__ Whh,          // [512][128]
    const float* __restrict__ w_tp,         // [128]
    const float* __restrict__ b_tp,         // [128]
    float* __restrict__ out)                // S*B*H outputs, then h, then c
{
  __shared__ __align__(16) _Float16 hbuf[2][H_SZ];   // ping-pong prev-h
  __shared__ __align__(16) float    tml[S_LEN];      // staged timep[.,b] 8KB
  const int tid = threadIdx.x;
  const int b   = blockIdx.x;                // one batch per WG
  const int tt  = tid & 3;
  const int col = tid >> 2;
  const int j   = tt * 128 + col;

  const float LOG2E = 1.4426950408889634f;

  // Stage this batch's time column into LDS (one-time, 4 loads/thread).
  #pragma unroll
  for (int k = 0; k < 4; ++k) {
    const int idx = tid + k * 512;
    tml[idx] = timep[(idx << 6) + b];
  }

  // Pre-scaled f16 weights in 16 NAMED registers: wTI = sc(T) *
  // W_hh[T*128+col][I*32+tt*8 .. +7].
  half8 w00, w01, w02, w03, w10, w11, w12, w13;
  half8 w20, w21, w22, w23, w30, w31, w32, w33;
  {
    const float s1 = -LOG2E, s2 = -2.0f * LOG2E;
    const float* r0 = Whh + (size_t)(0 * 128 + col) * H_SZ + tt * 8;
    const float* r1 = Whh + (size_t)(1 * 128 + col) * H_SZ + tt * 8;
    const float* r2 = Whh + (size_t)(2 * 128 + col) * H_SZ + tt * 8;
    const float* r3 = Whh + (size_t)(3 * 128 + col) * H_SZ + tt * 8;
    w00 = wcvt(r0 +  0, s1); w01 = wcvt(r0 + 32, s1);
    w02 = wcvt(r0 + 64, s1); w03 = wcvt(r0 + 96, s1);
    w10 = wcvt(r1 +  0, s1); w11 = wcvt(r1 + 32, s1);
    w12 = wcvt(r1 + 64, s1); w13 = wcvt(r1 + 96, s1);
    w20 = wcvt(r2 +  0, s2); w21 = wcvt(r2 + 32, s2);
    w22 = wcvt(r2 + 64, s2); w23 = wcvt(r2 + 96, s2);
    w30 = wcvt(r3 +  0, s1); w31 = wcvt(r3 + 32, s1);
    w32 = wcvt(r3 + 64, s1); w33 = wcvt(r3 + 96, s1);
  }

  float wt = -LOG2E * w_tp[col];
  float bt = -LOG2E * b_tp[col];
  const float am  = (tt == 2) ? 2.0f : 1.0f;
  const float aa  = (tt == 2) ? -1.0f : 0.0f;
  const bool  odd = (tt & 1) != 0;

  if (tid < 2 * H_SZ) ((_Float16*)hbuf)[tid] = (_Float16)0.0f;
  __syncthreads();

  // This thread's gate-x row (transposed layout): 2048 consecutive f16.
  const _Float16* gxr = gx + ((size_t)b * G4 + j) * S_LEN;
  const size_t bH = (size_t)b * H_SZ;

  // Double-buffered half8 blocks, 2 blocks (~16 substeps) ahead of use.
  half8 cur8 = *(const half8*)(gxr + 255 * 8);
  half8 nxt8 = *(const half8*)(gxr + 254 * 8);

  float c = 0.0f;

  for (int blk = 255; blk >= 0; --blk) {
    PIN_WEIGHTS();
    const int pfb = (blk >= 2) ? blk - 2 : 0;
    half8 fut8 = *(const half8*)(gxr + pfb * 8);
    const floatx4 tmA = *(const floatx4*)(&tml[blk * 8 + 4]); // t = +4..+7
    const floatx4 tmB = *(const floatx4*)(&tml[blk * 8 + 0]); // t = +0..+3

    // 8 substeps: t = blk*8+7 down to blk*8 (ping-pong parity returns to 0)
    SUB(7, tmA.w, 0, 1)
    SUB(6, tmA.z, 1, 0)
    SUB(5, tmA.y, 0, 1)
    SUB(4, tmA.x, 1, 0)
    SUB(3, tmB.w, 0, 1)
    SUB(2, tmB.z, 1, 0)
    SUB(1, tmB.y, 0, 1)
    SUB(0, tmB.x, 1, 0)

    cur8 = nxt8;
    nxt8 = fut8;
  }
}

// ---------------------------------------------------------------------------
extern "C" void kernel_launch(void* const* d_in, const int* in_sizes, int n_in,
                              void* d_out, int out_size, void* d_ws, size_t ws_size,
                              hipStream_t stream) {
  const float* input = (const float*)d_in[0];   // (S,B,D)
  const float* timep = (const float*)d_in[1];   // (S,B,1)
  const float* W_ih  = (const float*)d_in[2];   // (4H,D)
  const float* W_hh  = (const float*)d_in[3];   // (4H,H)
  const float* bias  = (const float*)d_in[4];   // (4H,)
  const float* w_t   = (const float*)d_in[5];   // (H,)
  const float* b_t   = (const float*)d_in[6];   // (H,)
  float* out = (float*)d_out;

  _Float16* gx = (_Float16*)d_ws;   // 64*512*2048*2 = 128 MiB, [b][n][t]

  gx_gemm<<<dim3(S_LEN / 256, B_SZ), dim3(256), 0, stream>>>(
      input, W_ih, bias, gx);

  lstm_rev<<<dim3(B_SZ), dim3(512), 0, stream>>>(
      gx, timep, W_hh, w_t, b_t, out);
}